// Round 5
// baseline (559.409 us; speedup 1.0000x reference)
//
#include <hip/hip_runtime.h>
#include <hip/hip_bf16.h>
#include <hip/hip_fp16.h>
#include <math.h>

// ScatterEdges: out[n,48] = segsum(x*sw, src) - segsum(x*sw, dst)
// E = 1.6M, N = 50000, D = 48.
//
// R1: direct f32 atomics -> 1940us (atomic-RMW-rate bound).
// R2: counting sort + wave-per-node gather -> 917us.
// R5: bucket multi-split + in-LDS sort + wave-per-node gather -> 622us.
// R6: gather float4 lanes + __shfl broadcast -> 581us (gather 197 @ 2.94TB/s).
// R7: f16 pre-pass xw=f16(x*sw) -> 590us (serial convert ~80us ate the win).
// R8: convert fused into hist/bin/sort + 128B padded rows -> 561us.
// R9: nt hints + hist/scan deleted (fixed-cap bucket regions) -> 544us.
// R10: launch_bounds (256,8) + item-word prefetch -> 540.7us (-3.5 only).
//     Wave count was NOT the limiter: the per-lane guard `if (idx<rem)`
//     around every row-load splits the k-loop into 8 exec-masked micro
//     blocks -> compiler can't cluster loads -> ~1-2 outstanding rows/wave.
//     And mean cnt = 64 -> the guarded (partial-chunk) path is the COMMON
//     path, so most items took the serialized code.
// R11 (this): fully BRANCHLESS chunk loop. Item words are clamp-loaded, so
//     its[k] is always a valid item -> row load always safe. Replace the
//     guard with bitmasks: word = (q ^ signmask) & validmask (+0.0 when
//     invalid). One straight-line block per chunk: 8 shfls -> 8 back-to-back
//     global_load_dwordx4 (MLP=8/wave) -> masked cvt/acc. its[8]+q[8] only
//     live arrays (~60 VGPR, fits (256,8) = 32 waves/CU). ~256 lines/CU in
//     flight. Predict gather ~90 -> 50-65us, total -> ~500-515.
//     If <10us gain: random-line service rate is the wall -> roofline.

#define D_FEAT 48
#define RNODES 64                  // nodes per bucket (bucket = node>>6)
#define RSHIFT 6
#define NB_MAX 1024                // supports N <= 65536
#define EPB 4096                   // edges per block in bin (256 thr x 16)
#define SORT_CAP 8192              // bucket region + LDS sort capacity (32KB)
#define ROW_U4 8                   // xwh row = 8 uint4 = 128B (48 f16 + pad)

typedef float v4f __attribute__((ext_vector_type(4)));

// ---- convert worklet: thread g produces 16B chunk r=g&7 of row e=g>>3.
//      x reads are NON-TEMPORAL: x (307MB) must not evict xwh from L3. ----
__device__ __forceinline__ void convert_one(int g, const float* __restrict__ x,
                                            const float* __restrict__ sw,
                                            uint4* __restrict__ xwh) {
    int e = g >> 3, r = g & 7;
    uint4 o = make_uint4(0u, 0u, 0u, 0u);
    if (r < 6) {
        float s = sw[e];
        const v4f* px = (const v4f*)x + (size_t)e * 12 + r * 2;
        v4f a = __builtin_nontemporal_load(px);
        v4f b = __builtin_nontemporal_load(px + 1);
        __half2 h0 = __floats2half2_rn(a.x * s, a.y * s);
        __half2 h1 = __floats2half2_rn(a.z * s, a.w * s);
        __half2 h2 = __floats2half2_rn(b.x * s, b.y * s);
        __half2 h3 = __floats2half2_rn(b.z * s, b.w * s);
        o.x = __builtin_bit_cast(unsigned int, h0);
        o.y = __builtin_bit_cast(unsigned int, h1);
        o.z = __builtin_bit_cast(unsigned int, h2);
        o.w = __builtin_bit_cast(unsigned int, h3);
    }
    xwh[g] = o;   // normal store: WANT this resident in L3
}

// ---- k1: multi-split binning into fixed-capacity bucket regions
//          (+ fused convert chunk). gcur pre-zeroed; lbase = b*CAP + resv ----
__device__ __forceinline__ void bin_place(int e, int node, int side,
                                          int* lh, const int* lbase,
                                          int* __restrict__ items) {
    int b = node >> RSHIFT;
    int p = lbase[b] + atomicAdd(&lh[b], 1);
    items[p] = (e << 7) | (side << 6) | (node & (RNODES - 1));
}

__global__ __launch_bounds__(256) void bin_cv_kernel(
        const int* __restrict__ src, const int* __restrict__ dst,
        int* __restrict__ gcur, int* __restrict__ items, int E, int NB,
        int role_blocks,
        const float* __restrict__ x, const float* __restrict__ sw,
        uint4* __restrict__ xwh, int cv_g0, int cv_g1) {
    __shared__ int lh[NB_MAX];     // phase A: local hist; phase C: local cursor
    __shared__ int lbase[NB_MAX];  // reserved global base per bucket
    if (blockIdx.x >= role_blocks) {
        int g = cv_g0 + (blockIdx.x - role_blocks) * 256 + threadIdx.x;
        if (g < cv_g1) convert_one(g, x, sw, xwh);
        return;
    }
    for (int b = threadIdx.x; b < NB; b += 256) lh[b] = 0;
    __syncthreads();
    int t = threadIdx.x;
    int base = blockIdx.x * EPB;
    #pragma unroll
    for (int i = 0; i < EPB / 1024; ++i) {
        int e = base + i * 1024 + t * 4;
        if (e + 3 < E) {
            int4 s4 = *(const int4*)(src + e);
            int4 d4 = *(const int4*)(dst + e);
            atomicAdd(&lh[s4.x >> RSHIFT], 1);
            atomicAdd(&lh[s4.y >> RSHIFT], 1);
            atomicAdd(&lh[s4.z >> RSHIFT], 1);
            atomicAdd(&lh[s4.w >> RSHIFT], 1);
            atomicAdd(&lh[d4.x >> RSHIFT], 1);
            atomicAdd(&lh[d4.y >> RSHIFT], 1);
            atomicAdd(&lh[d4.z >> RSHIFT], 1);
            atomicAdd(&lh[d4.w >> RSHIFT], 1);
        } else {
            for (int j = 0; j < 4; ++j) {
                int ee = e + j;
                if (ee < E) {
                    atomicAdd(&lh[src[ee] >> RSHIFT], 1);
                    atomicAdd(&lh[dst[ee] >> RSHIFT], 1);
                }
            }
        }
    }
    __syncthreads();
    for (int b = threadIdx.x; b < NB; b += 256) {
        int c = lh[b];
        lbase[b] = b * SORT_CAP + (c ? atomicAdd(&gcur[b], c) : 0);
        lh[b] = 0;  // becomes local cursor
    }
    __syncthreads();
    #pragma unroll
    for (int i = 0; i < EPB / 1024; ++i) {
        int e = base + i * 1024 + t * 4;
        if (e + 3 < E) {
            int4 s4 = *(const int4*)(src + e);
            int4 d4 = *(const int4*)(dst + e);
            bin_place(e + 0, s4.x, 0, lh, lbase, items);
            bin_place(e + 1, s4.y, 0, lh, lbase, items);
            bin_place(e + 2, s4.z, 0, lh, lbase, items);
            bin_place(e + 3, s4.w, 0, lh, lbase, items);
            bin_place(e + 0, d4.x, 1, lh, lbase, items);
            bin_place(e + 1, d4.y, 1, lh, lbase, items);
            bin_place(e + 2, d4.z, 1, lh, lbase, items);
            bin_place(e + 3, d4.w, 1, lh, lbase, items);
        } else {
            for (int j = 0; j < 4; ++j) {
                int ee = e + j;
                if (ee < E) {
                    bin_place(ee, src[ee], 0, lh, lbase, items);
                    bin_place(ee, dst[ee], 1, lh, lbase, items);
                }
            }
        }
    }
}

// ---- k2: in-LDS counting sort per bucket region (+ fused convert chunk);
//          emits per-node noff (start) and ncnt (count) ----
__global__ __launch_bounds__(256) void sort_cv_kernel(
        int* __restrict__ items, const int* __restrict__ gcur,
        int* __restrict__ noff, int* __restrict__ ncnt, int N,
        int role_blocks,
        const float* __restrict__ x, const float* __restrict__ sw,
        uint4* __restrict__ xwh, int cv_g0, int cv_g1) {
    __shared__ int sitems[SORT_CAP];           // 32 KB
    __shared__ int ccnt[RNODES];
    __shared__ int cbase[RNODES];
    if (blockIdx.x >= role_blocks) {
        int g = cv_g0 + (blockIdx.x - role_blocks) * 256 + threadIdx.x;
        if (g < cv_g1) convert_one(g, x, sw, xwh);
        return;
    }
    int r = blockIdx.x;
    int lo = r * SORT_CAP;
    int cnt = min(gcur[r], SORT_CAP);          // host-guarded <= SORT_CAP
    int t = threadIdx.x;

    if (t < RNODES) ccnt[t] = 0;
    __syncthreads();
    #pragma unroll 4
    for (int i = t; i < cnt; i += 256) {
        int it = items[lo + i];
        sitems[i] = it;
        atomicAdd(&ccnt[it & (RNODES - 1)], 1);
    }
    __syncthreads();
    if (t < RNODES) {                          // wave 0: 64-lane inclusive scan
        int c = ccnt[t];
        int v = c;
        #pragma unroll
        for (int d = 1; d < 64; d <<= 1) {
            int a = __shfl_up(v, d);
            if (t >= d) v += a;
        }
        int excl = v - c;
        cbase[t] = excl;
        int n = r * RNODES + t;
        if (n < N) {
            noff[n] = lo + excl;
            ncnt[n] = c;
        }
        ccnt[t] = 0;                           // becomes cursor
    }
    __syncthreads();
    #pragma unroll 4
    for (int i = t; i < cnt; i += 256) {
        int it = sitems[i];
        int loc = it & (RNODES - 1);
        int p = cbase[loc] + atomicAdd(&ccnt[loc], 1);
        items[lo + p] = it;
    }
}

// ---- k3 (f16 path): gather — one wave per node, 8 groups x 8 lanes.
//      xw row = 128B aligned = one cache line. BRANCHLESS chunk loop:
//      clamp-loaded item words make every its[k] valid, so row loads are
//      unconditional (8 clustered loads in flight per wave); invalid lanes
//      are zeroed via bitmask, sign applied via XOR. ----
__global__ __launch_bounds__(256, 8) void gather_f16_kernel(
        const uint4* __restrict__ xwh, const int* __restrict__ noff,
        const int* __restrict__ ncnt, const int* __restrict__ items,
        float* __restrict__ out, int N) {
    int n = (blockIdx.x * blockDim.x + threadIdx.x) >> 6;
    int lane = threadIdx.x & 63;
    if (n >= N) return;

    int lo = noff[n];
    int cnt = ncnt[n];
    int grp = lane >> 3;        // 0..3..7: which item of an 8-item pack
    int sub = lane & 7;         // 0..7: uint4 column (6,7 = zero pad)

    float4 acc0 = make_float4(0.f, 0.f, 0.f, 0.f);
    float4 acc1 = make_float4(0.f, 0.f, 0.f, 0.f);

    if (cnt > 0) {
        const int* ip = items + lo;
        const uint4* xb = xwh + sub;
        int chunk = __builtin_nontemporal_load(ip + min(lane, cnt - 1));
        for (int cb = 0; cb < cnt; cb += 64) {
            int rem = cnt - cb;
            // prefetch next chunk's item word (clamped -> always safe;
            // harmless duplicate load on the last iteration)
            int chunk_next = __builtin_nontemporal_load(
                ip + min(cb + 64 + lane, cnt - 1));

            int its[8];
            #pragma unroll
            for (int k = 0; k < 8; ++k)
                its[k] = __shfl(chunk, k * 8 + grp);

            uint4 q[8];
            #pragma unroll
            for (int k = 0; k < 8; ++k)
                q[k] = xb[(size_t)(unsigned)(its[k] >> 7) * ROW_U4];

            #pragma unroll
            for (int k = 0; k < 8; ++k) {
                unsigned sm = (its[k] & RNODES) ? 0x80008000u : 0u;
                unsigned vv = (k * 8 + grp < rem) ? 0xFFFFFFFFu : 0u;
                unsigned w0 = (q[k].x ^ sm) & vv;
                unsigned w1 = (q[k].y ^ sm) & vv;
                unsigned w2 = (q[k].z ^ sm) & vv;
                unsigned w3 = (q[k].w ^ sm) & vv;
                float2 f0 = __half22float2(__builtin_bit_cast(__half2, w0));
                float2 f1 = __half22float2(__builtin_bit_cast(__half2, w1));
                float2 f2 = __half22float2(__builtin_bit_cast(__half2, w2));
                float2 f3 = __half22float2(__builtin_bit_cast(__half2, w3));
                acc0.x += f0.x; acc0.y += f0.y; acc0.z += f1.x; acc0.w += f1.y;
                acc1.x += f2.x; acc1.y += f2.y; acc1.z += f3.x; acc1.w += f3.y;
            }
            chunk = chunk_next;
        }
    }

    // fold 8 groups down to grp 0 (lanes 0..7); sub preserved by +8k shfls
    #pragma unroll
    for (int d = 32; d >= 8; d >>= 1) {
        acc0.x += __shfl_down(acc0.x, d);
        acc0.y += __shfl_down(acc0.y, d);
        acc0.z += __shfl_down(acc0.z, d);
        acc0.w += __shfl_down(acc0.w, d);
        acc1.x += __shfl_down(acc1.x, d);
        acc1.y += __shfl_down(acc1.y, d);
        acc1.z += __shfl_down(acc1.z, d);
        acc1.w += __shfl_down(acc1.w, d);
    }

    if (lane < 6) {
        v4f o0 = {acc0.x, acc0.y, acc0.z, acc0.w};
        v4f o1 = {acc1.x, acc1.y, acc1.z, acc1.w};
        v4f* orow = (v4f*)(out + (size_t)n * D_FEAT);
        __builtin_nontemporal_store(o0, orow + lane * 2);
        __builtin_nontemporal_store(o1, orow + lane * 2 + 1);
    }
}

// ---- k3 (f32 fallback path): one wave per node, 4 groups x 12 lanes ----
__global__ __launch_bounds__(256, 4) void gather_kernel(
        const float4* __restrict__ x4, const float* __restrict__ sw,
        const int* __restrict__ noff, const int* __restrict__ ncnt,
        const int* __restrict__ items, float* __restrict__ out, int N) {
    int n = (blockIdx.x * blockDim.x + threadIdx.x) >> 6;
    int lane = threadIdx.x & 63;
    if (n >= N) return;

    int lo = noff[n];
    int cnt = ncnt[n];
    int grp = lane >> 4;        // 0..3: which item of a 4-item pack
    int sub = lane & 15;        // 0..15: float4 column index (active <12)

    float4 acc = make_float4(0.f, 0.f, 0.f, 0.f);

    for (int cb = 0; cb < cnt; cb += 64) {
        int chunk = items[lo + min(cb + lane, cnt - 1)];
        int rem = cnt - cb;
        #pragma unroll
        for (int k = 0; k < 16; ++k) {
            int idx = k * 4 + grp;            // 0..63
            int it = __shfl(chunk, idx);
            int e = it >> 7;
            float w = (idx < rem) ? sw[e] : 0.f;
            w = (it & RNODES) ? -w : w;
            if (sub < 12) {
                float4 v = x4[(size_t)e * 12 + sub];
                acc.x += w * v.x;
                acc.y += w * v.y;
                acc.z += w * v.z;
                acc.w += w * v.w;
            }
        }
    }

    acc.x += __shfl_down(acc.x, 32);
    acc.y += __shfl_down(acc.y, 32);
    acc.z += __shfl_down(acc.z, 32);
    acc.w += __shfl_down(acc.w, 32);
    acc.x += __shfl_down(acc.x, 16);
    acc.y += __shfl_down(acc.y, 16);
    acc.z += __shfl_down(acc.z, 16);
    acc.w += __shfl_down(acc.w, 16);

    if (lane < 12) {
        float4* orow = (float4*)(out + (size_t)n * D_FEAT);
        orow[lane] = acc;
    }
}

// ---- fallback: direct atomic scatter (correct, slow) ----
#define TPE 12
__global__ void atomic_fallback_kernel(const float4* __restrict__ x,
                                       const float* __restrict__ sw,
                                       const int* __restrict__ src,
                                       const int* __restrict__ dst,
                                       float* __restrict__ out, int n_edges) {
    int g = blockIdx.x * blockDim.x + threadIdx.x;
    int e = g / TPE;
    int q = g - e * TPE;
    if (e >= n_edges) return;
    float s = sw[e];
    float4 v = x[(size_t)e * TPE + q];
    v.x *= s; v.y *= s; v.z *= s; v.w *= s;
    int si = src[e], di = dst[e];
    float* po = out + (size_t)si * D_FEAT + q * 4;
    unsafeAtomicAdd(po + 0, v.x);
    unsafeAtomicAdd(po + 1, v.y);
    unsafeAtomicAdd(po + 2, v.z);
    unsafeAtomicAdd(po + 3, v.w);
    float* pd = out + (size_t)di * D_FEAT + q * 4;
    unsafeAtomicAdd(pd + 0, -v.x);
    unsafeAtomicAdd(pd + 1, -v.y);
    unsafeAtomicAdd(pd + 2, -v.z);
    unsafeAtomicAdd(pd + 3, -v.w);
}

extern "C" void kernel_launch(void* const* d_in, const int* in_sizes, int n_in,
                              void* d_out, int out_size, void* d_ws, size_t ws_size,
                              hipStream_t stream) {
    const float* x  = (const float*)d_in[0];
    const float* sw = (const float*)d_in[1];
    const int*   src = (const int*)d_in[2];
    const int*   dst = (const int*)d_in[3];
    float* out = (float*)d_out;

    int E = in_sizes[1];   // switch: [E]
    int N = in_sizes[4];   // species: [N]
    int NB = (N + RNODES - 1) / RNODES;

    // ws layout (f16 path): xwh[E rows x 128B] | gcur[NB] | noff[N] | ncnt[N]
    //                       | items[NB*SORT_CAP]
    size_t xwh_bytes = (size_t)E * ROW_U4 * 16;   // 128B per edge row
    size_t need_int  = ((size_t)NB + 2 * (size_t)N
                        + (size_t)NB * SORT_CAP) * sizeof(int);
    size_t need_f16  = xwh_bytes + need_int;

    // bucket capacity guard: mean + 16 sigma must fit (uniform-random nodes)
    int mean = (NB > 0) ? (int)((long long)2 * E / NB) : 0;
    bool bucket_risk = mean + 16 * (int)sqrtf((float)(mean > 0 ? mean : 1)) > SORT_CAP;

    if (NB > NB_MAX || ws_size < need_int || bucket_risk) {
        hipMemsetAsync(d_out, 0, (size_t)out_size * sizeof(float), stream);
        long long total = (long long)E * TPE;
        int grid = (int)((total + 255) / 256);
        atomic_fallback_kernel<<<grid, 256, 0, stream>>>(
            (const float4*)x, sw, src, dst, out, E);
        return;
    }

    bool use_f16 = (ws_size >= need_f16);
    char* base = (char*)d_ws;
    uint4* xwh = (uint4*)base;
    int* ints  = (int*)(use_f16 ? (base + xwh_bytes) : base);

    int* gcur  = ints;
    int* noff  = gcur + NB;
    int* ncnt  = noff + N;
    int* items = ncnt + N;

    hipMemsetAsync(gcur, 0, (size_t)NB * sizeof(int), stream);

    // convert work split into 2 chunks fused with bin / sort
    int G = use_f16 ? E * 8 : 0;              // one thread per 16B row chunk
    int cvb = (G + 255) / 256;
    int c1 = cvb / 2, c2 = cvb - c1;
    int g1 = c1 * 256;

    int eblk = (E + EPB - 1) / EPB;

    bin_cv_kernel<<<eblk + c1, 256, 0, stream>>>(
        src, dst, gcur, items, E, NB, eblk,
        x, sw, xwh, 0, min(g1, G));
    sort_cv_kernel<<<NB + c2, 256, 0, stream>>>(
        items, gcur, noff, ncnt, N, NB,
        x, sw, xwh, g1, G);

    int gblk = (int)(((long long)N * 64 + 255) / 256);
    if (use_f16) {
        gather_f16_kernel<<<gblk, 256, 0, stream>>>(
            (const uint4*)xwh, noff, ncnt, items, out, N);
    } else {
        gather_kernel<<<gblk, 256, 0, stream>>>(
            (const float4*)x, sw, noff, ncnt, items, out, N);
    }
}